// Round 2
// baseline (90.057 us; speedup 1.0000x reference)
//
#include <hip/hip_runtime.h>
#include <hip/hip_bf16.h>

#define NV 50000

// ws layout:
//   [0, 32768)        AhTs packed f16x2, B-frag quad order; columns SIGMA-permuted:
//                     od = h*64 + c*8 + o  (std d = o*8 + c)
//   [32768, 33792)    rbar f32 [256] (sigma order)
//   [33792, 34304)    wvh  packed f16x2 [8 i][4 h][4 jp] (W_V, std order)
//   [34816, +6.4MB)   xh   packed f16x2 [NV][32]         (x converted)

typedef _Float16 h2_t __attribute__((ext_vector_type(2)));
typedef _Float16 f16x4 __attribute__((ext_vector_type(4)));
typedef _Float16 f16x8 __attribute__((ext_vector_type(8)));
typedef float f32x4 __attribute__((ext_vector_type(4)));
typedef float f32x16 __attribute__((ext_vector_type(16)));

#if defined(__has_builtin)
#if __has_builtin(__builtin_amdgcn_fdot2)
#define HAVE_FDOT2 1
#endif
#endif

__device__ __forceinline__ float fdot2f(h2_t a, h2_t b, float c) {
#ifdef HAVE_FDOT2
  return __builtin_amdgcn_fdot2(a, b, c, false);
#else
  return fmaf((float)a.x, (float)b.x, fmaf((float)a.y, (float)b.y, c));
#endif
}
__device__ __forceinline__ h2_t u2h(unsigned u) {
  union { unsigned u; h2_t h; } c; c.u = u; return c.h;
}
__device__ __forceinline__ unsigned pk2(float a, float b) {
  auto v = __builtin_amdgcn_cvt_pkrtz(a, b);
  union { decltype(v) h; unsigned u; } c; c.h = v; return c.u;
}
__device__ __forceinline__ f16x8 u4h8(uint4 u) {
  union { uint4 u; f16x8 h; } c; c.u = u; return c.h;
}
__device__ __forceinline__ f16x4 u2h4(uint2 u) {
  union { uint2 u; f16x4 h; } c; c.u = u; return c.h;
}
// IR-level memory clobber + HW LDS drain + scheduler pin (rule #18)
__device__ __forceinline__ void lds_fence() {
  asm volatile("s_waitcnt lgkmcnt(0)" ::: "memory");
  __builtin_amdgcn_sched_barrier(0);
}

__global__ void setup_kernel(const float* __restrict__ WQ, const float* __restrict__ WQb,
                             const float* __restrict__ WK,
                             const float* __restrict__ bases, const float* __restrict__ coeffs,
                             unsigned* __restrict__ AhTs, float* __restrict__ rbar,
                             unsigned* __restrict__ wvh) {
  int ep = blockIdx.x;      // 0..31 (e-pair)
  int od = threadIdx.x;     // 0..255 : sigma column h*64 + c*8 + o
  int h = od >> 6;
  int js = od & 63;                           // sigma index c*8+o
  int dstd = ((js & 7) << 3) | (js >> 3);     // std WK column o*8+c
  int e0 = ep * 2;
  float s0 = 0.f, s1 = 0.f;
#pragma unroll 4
  for (int k = 0; k < 64; ++k) {
    float wk = WK[(h * 64 + k) * 64 + dstd];
    s0 += WQ[(h * 64 + k) * 64 + e0] * wk;
    s1 += WQ[(h * 64 + k) * 64 + e0 + 1] * wk;
  }
  // B-frag quad order: one uint4 = eps {eq*4+0..3} for a fixed od
  AhTs[((ep >> 2) * 256 + od) * 4 + (ep & 3)] = pk2(s0 * 0.125f, s1 * 0.125f);
  if (ep == 0) {
    float r = 0.f;
    for (int k = 0; k < 64; ++k) r += WQb[h * 64 + k] * WK[(h * 64 + k) * 64 + dstd];
    rbar[od] = r * 0.125f;
    if (od < 128) {   // wvh[i][h][jp]  (std: contraction over channel j)
      int i = od >> 4, hh = (od >> 2) & 3, jp = od & 3;
      float w0 = 0.f, w1 = 0.f;
      for (int b = 0; b < 6; ++b) {
        w0 += coeffs[hh * 6 + b] * bases[b * 64 + i * 8 + 2 * jp];
        w1 += coeffs[hh * 6 + b] * bases[b * 64 + i * 8 + 2 * jp + 1];
      }
      wvh[od] = pk2(w0, w1);
    }
  }
}

// x (f32) -> xh (packed f16x2), vectorized: 8 floats -> 1 uint4 per thread
__global__ void xconv_kernel(const float* __restrict__ x, unsigned* __restrict__ xh) {
  int idx = blockIdx.x * 256 + threadIdx.x;   // uint4 index, 0 .. NV*8-1
  if (idx < NV * 8) {
    float4 a = ((const float4*)x)[idx * 2];
    float4 b = ((const float4*)x)[idx * 2 + 1];
    uint4 o;
    o.x = pk2(a.x, a.y);
    o.y = pk2(a.z, a.w);
    o.z = pk2(b.x, b.y);
    o.w = pk2(b.z, b.w);
    ((uint4*)xh)[idx] = o;
  }
}

// ---------------- attention: 1 wave = 1 vertex.
// f' via 4x mfma_f32_32x32x16_f16 (m-block-diagonal, operands direct from global);
// scores via 16x16x32 on sigma-ordered Ftr/q16; softmax + e^ fully in-register;
// g via 4x mfma 16x16x16f16 (B-frag = scores C-layout); epilogue unchanged. ----------------
__global__ __launch_bounds__(256, 5) void attn_kernel(
    const unsigned* __restrict__ xh, const int* __restrict__ nbr,
    const float* __restrict__ P, const unsigned* __restrict__ AhTs,
    const float* __restrict__ rbar, const unsigned* __restrict__ wvh,
    float* __restrict__ out) {
  __shared__ __align__(16) _Float16 q16[4][256];     // 2 KB   [vi][h*64+js] (sigma)
  __shared__ __align__(16) _Float16 Ftr[4][1152];    // 9 KB   [m][72-stride], sigma rows js=c*8+o
  __shared__ __align__(16) _Float16 g16[4][4][72];   // 2.25KB [w][h][jstd] (+pad)

  const int t = threadIdx.x;
  const int w = t >> 6, lane = t & 63;
  const int v0 = blockIdx.x * 4;
  const int v = v0 + w;    // this wave's vertex
  const int c_ep = lane >> 3, i_ep = lane & 7;
  const char* xhb = (const char*)xh;

  // ---- f'-MFMA lane decomposition (32x32x16: row/col = lane&31 = fm*8+fc) ----
  const int fm = (lane >> 3) & 3;       // m sub-block 0..3 within a 4-m group
  const int fc = lane & 7;              // A-role: o (P row) ; B-role: c (X channel)
  const int fh = lane >> 5;             // k-group (j octet)
  const bool act = (fh == (fm & 1));    // A lane carries P data iff parity matches

  // ---- early global loads: X B-frags (gather, f16) ----
  uint4 xb[4];
#pragma unroll
  for (int b = 0; b < 4; ++b) {
    int nb = nbr[(size_t)v * 16 + b * 4 + fm];
    xb[b] = *(const uint4*)(xhb + (size_t)nb * 128 + fc * 16);
  }
  // ---- early global loads: P A-frags (f32 -> f16, parity-zeroed) ----
  f16x8 pa[4];
#pragma unroll
  for (int b = 0; b < 4; ++b) {
#pragma unroll
    for (int i = 0; i < 8; ++i) pa[b][i] = (_Float16)0.f;
  }
  if (act) {
#pragma unroll
    for (int b = 0; b < 4; ++b) {
      const float4* pr = (const float4*)(P + (size_t)v * 1024 + (size_t)(b * 4 + fm) * 64 + fc * 8);
      float4 r0 = pr[0], r1 = pr[1];
      union { uint4 u; f16x8 h; } pc;
      pc.u.x = pk2(r0.x, r0.y); pc.u.y = pk2(r0.z, r0.w);
      pc.u.z = pk2(r1.x, r1.y); pc.u.w = pk2(r1.z, r1.w);
      pa[b] = pc.h;
    }
  }

  // ---- rbar for q16 write (writer lanes<16) ----
  float rbq[4];
#pragma unroll
  for (int tt = 0; tt < 4; ++tt) rbq[tt] = rbar[w * 64 + tt * 16 + (lane & 15)];

  // ---- q~ via MFMA: C[vi][od] = sum_e x[v0+vi][e] A~[e][od] (sigma columns) ----
  {
    const int od0 = w * 64;
    const uint4* xrow4 = (const uint4*)(xh + (size_t)(v0 + (lane & 3)) * 32);
    f16x8 afrag0 = u4h8(xrow4[(lane >> 4)]);       // K-step 0: e 0..31
    f16x8 afrag1 = u4h8(xrow4[4 + (lane >> 4)]);   // K-step 1: e 32..63

    f32x4 acc[4];
#pragma unroll
    for (int tt = 0; tt < 4; ++tt) acc[tt] = (f32x4){0.f, 0.f, 0.f, 0.f};

#pragma unroll
    for (int tt = 0; tt < 4; ++tt) {
      const int colbase = od0 + tt * 16 + (lane & 15);
#pragma unroll
      for (int s = 0; s < 2; ++s) {
        uint4 bu = *(const uint4*)&AhTs[((s * 4 + (lane >> 4)) * 256 + colbase) * 4];
        acc[tt] = __builtin_amdgcn_mfma_f32_16x16x32_f16(s ? afrag1 : afrag0, u4h8(bu),
                                                         acc[tt], 0, 0, 0);
      }
    }
    if (lane < 16) {
#pragma unroll
      for (int tt = 0; tt < 4; ++tt)
#pragma unroll
        for (int vi = 0; vi < 4; ++vi)
          q16[vi][od0 + tt * 16 + lane] = (_Float16)(acc[tt][vi] + rbq[tt]);
    }
  }
  __syncthreads();   // publishes q16 across waves

  // ---- hoisted scores B-frags (sigma order, matches Ftr rows) ----
  const int hb = (lane & 15) & 3;   // cols 4..15 duplicate h 0..3; outputs unused
  f16x8 bq0 = u4h8(*(const uint4*)&q16[w][hb * 64 + (lane >> 4) * 8]);
  f16x8 bq1 = u4h8(*(const uint4*)&q16[w][hb * 64 + 32 + (lane >> 4) * 8]);

  // ---- f' via 4x mfma 32x32x16 f16 ; D[(fm,o)][(fm,c)] diag -> Ftr sigma rows ----
  {
    f32x16 zf;
#pragma unroll
    for (int i = 0; i < 16; ++i) zf[i] = 0.f;
#pragma unroll
    for (int b = 0; b < 4; ++b) {
      f32x16 fa = __builtin_amdgcn_mfma_f32_32x32x16_f16(pa[b], u4h8(xb[b]), zf, 0, 0, 0);
      // useful regs: fa[fm*4 + t], o = fh*4 + t, at col (fm, fc=c)
      float f0 = (fm & 2) ? ((fm & 1) ? fa[12] : fa[8]) : ((fm & 1) ? fa[4] : fa[0]);
      float f1 = (fm & 2) ? ((fm & 1) ? fa[13] : fa[9]) : ((fm & 1) ? fa[5] : fa[1]);
      float f2 = (fm & 2) ? ((fm & 1) ? fa[14] : fa[10]) : ((fm & 1) ? fa[6] : fa[2]);
      float f3 = (fm & 2) ? ((fm & 1) ? fa[15] : fa[11]) : ((fm & 1) ? fa[7] : fa[3]);
      uint2 wv;
      wv.x = pk2(f0, f1);
      wv.y = pk2(f2, f3);
      // sigma index js = c*8 + o = fc*8 + fh*4 + t  -> contiguous b64
      *(uint2*)&Ftr[w][(b * 4 + fm) * 72 + fc * 8 + fh * 4] = wv;
    }
  }
  lds_fence();   // Ftr visible to this wave's scores + g reads

  // ---- scores via MFMA: S[m][h] = sum_js F[m][js] q16[h][js] ----
  f32x4 sac = (f32x4){0.f, 0.f, 0.f, 0.f};
  {
    f16x8 af0 = u4h8(*(const uint4*)&Ftr[w][(lane & 15) * 72 + (lane >> 4) * 8]);
    f16x8 af1 = u4h8(*(const uint4*)&Ftr[w][(lane & 15) * 72 + 32 + (lane >> 4) * 8]);
    sac = __builtin_amdgcn_mfma_f32_16x16x32_f16(af0, bq0, sac, 0, 0, 0);
    sac = __builtin_amdgcn_mfma_f32_16x16x32_f16(af1, bq1, sac, 0, 0, 0);
    // lane holds S[m=(lane>>4)*4+r][h=lane&15], r=0..3 (h<4 meaningful)
  }

  // ---- softmax fully in-register: e^ = exp(S)/s4 -> g-MFMA B-frag (k=m order) ----
  f16x4 eb;
  {
    float e0 = __expf(sac[0]), e1 = __expf(sac[1]);
    float e2 = __expf(sac[2]), e3 = __expf(sac[3]);
    float p = (e0 + e1) + (e2 + e3);
    p += __shfl_xor(p, 16);
    p += __shfl_xor(p, 32);
    float is = __builtin_amdgcn_rcpf(p);
    uint2 eu;
    eu.x = pk2(e0 * is, e1 * is);
    eu.y = pk2(e2 * is, e3 * is);
    eb = u2h4(eu);
  }

  // ---- epilogue weights (late load, overlaps g compute) ----
  uint4 wq[4];
#pragma unroll
  for (int h = 0; h < 4; ++h) wq[h] = *(const uint4*)&wvh[i_ep * 16 + h * 4];

  // ---- g via 4x mfma 16x16x16f16: g[h][jstd] = sum_m e^[m][h] F[m][jstd] ----
  {
    const int rl = lane & 15, kg = lane >> 4;
    const int go = rl >> 3, gc = rl & 7;   // jstd = b2*16 + rl = (2*b2+go)*8 + gc
#pragma unroll
    for (int b2 = 0; b2 < 4; ++b2) {
      f16x4 ga;
#pragma unroll
      for (int tt = 0; tt < 4; ++tt)
        ga[tt] = Ftr[w][(kg * 4 + tt) * 72 + gc * 8 + 2 * b2 + go];  // F[m=kg*4+tt][jstd]
      f32x4 zg = (f32x4){0.f, 0.f, 0.f, 0.f};
      f32x4 gacc = __builtin_amdgcn_mfma_f32_16x16x16f16(ga, eb, zg, 0, 0, 0);
      // D[row=kg*4+reg][col=h'=rl]: g[h'][b2*16 + kg*4 + reg], h'<4 useful
      if (rl < 4) {
        uint2 gv;
        gv.x = pk2(gacc[0], gacc[1]);
        gv.y = pk2(gacc[2], gacc[3]);
        *(uint2*)&g16[w][rl][b2 * 16 + kg * 4] = gv;
      }
    }
  }
  lds_fence();

  // ---- W_V epilogue (std order, unchanged) ----
#pragma unroll
  for (int h = 0; h < 4; ++h) {
    uint4 gq = *(const uint4*)&g16[w][h][c_ep * 8];
    float oacc = fdot2f(u2h(wq[h].x), u2h(gq.x),
                 fdot2f(u2h(wq[h].y), u2h(gq.y),
                 fdot2f(u2h(wq[h].z), u2h(gq.z),
                 fdot2f(u2h(wq[h].w), u2h(gq.w), 0.f))));
    out[(size_t)v * 256 + h * 64 + lane] = oacc;
  }
}

extern "C" void kernel_launch(void* const* d_in, const int* in_sizes, int n_in,
                              void* d_out, int out_size, void* d_ws, size_t ws_size,
                              hipStream_t stream) {
  const float* x      = (const float*)d_in[0];
  const int*   nbr    = (const int*)d_in[1];
  const float* P      = (const float*)d_in[2];
  // d_in[3] = rel_pos_u : unused by the reference
  const float* WQ     = (const float*)d_in[4];
  const float* WQb    = (const float*)d_in[5];
  const float* WK     = (const float*)d_in[6];
  // d_in[7] = W_K_b : softmax-invariant -> dropped
  const float* bases  = (const float*)d_in[8];
  const float* coeffs = (const float*)d_in[9];

  unsigned* AhTs = (unsigned*)d_ws;
  float* rbar   = (float*)((char*)d_ws + 32768);
  unsigned* wvh = (unsigned*)((char*)d_ws + 33792);
  unsigned* xh  = (unsigned*)((char*)d_ws + 34816);
  float* out    = (float*)d_out;

  hipLaunchKernelGGL(setup_kernel, dim3(32), dim3(256), 0, stream,
                     WQ, WQb, WK, bases, coeffs, AhTs, rbar, wvh);
  hipLaunchKernelGGL(xconv_kernel, dim3((NV * 8 + 255) / 256), dim3(256), 0, stream, x, xh);
  hipLaunchKernelGGL(attn_kernel, dim3(NV / 4), dim3(256), 0, stream,
                     xh, nbr, P, AhTs, rbar, wvh, out);
}

// Round 3
// 86.883 us; speedup vs baseline: 1.0365x; 1.0365x over previous
//
#include <hip/hip_runtime.h>
#include <hip/hip_bf16.h>

#define NV 50000

// ws layout:
//   [0, 32768)        AhTs packed f16x2, B-frag quad order: [eq=ep>>2][od][r=ep&3]
//   [32768, 33792)    rbar f32 [256]
//   [33792, 34304)    wvh  packed f16x2 [8 i][4 h][4 jp] (W_V)
//   [34816, +6.4MB)   xh   packed f16x2 [NV][32]         (x converted)

typedef _Float16 h2_t __attribute__((ext_vector_type(2)));
typedef _Float16 f16x4 __attribute__((ext_vector_type(4)));
typedef _Float16 f16x8 __attribute__((ext_vector_type(8)));
typedef float f32x4 __attribute__((ext_vector_type(4)));

#if defined(__has_builtin)
#if __has_builtin(__builtin_amdgcn_fdot2)
#define HAVE_FDOT2 1
#endif
#endif

__device__ __forceinline__ float fdot2f(h2_t a, h2_t b, float c) {
#ifdef HAVE_FDOT2
  return __builtin_amdgcn_fdot2(a, b, c, false);
#else
  return fmaf((float)a.x, (float)b.x, fmaf((float)a.y, (float)b.y, c));
#endif
}
__device__ __forceinline__ h2_t u2h(unsigned u) {
  union { unsigned u; h2_t h; } c; c.u = u; return c.h;
}
__device__ __forceinline__ unsigned pk2(float a, float b) {
  auto v = __builtin_amdgcn_cvt_pkrtz(a, b);   // __fp16 ext_vector(2)
  union { decltype(v) h; unsigned u; } c; c.h = v; return c.u;
}
__device__ __forceinline__ f16x8 u4h8(uint4 u) {
  union { uint4 u; f16x8 h; } c; c.u = u; return c.h;
}
__device__ __forceinline__ f16x4 u2h4(uint2 u) {
  union { uint2 u; f16x4 h; } c; c.u = u; return c.h;
}
// IR-level memory clobber + HW LDS drain + scheduler pin (rule #18)
__device__ __forceinline__ void lds_fence() {
  asm volatile("s_waitcnt lgkmcnt(0)" ::: "memory");
  __builtin_amdgcn_sched_barrier(0);
}

__global__ void setup_kernel(const float* __restrict__ WQ, const float* __restrict__ WQb,
                             const float* __restrict__ WK,
                             const float* __restrict__ bases, const float* __restrict__ coeffs,
                             unsigned* __restrict__ AhTs, float* __restrict__ rbar,
                             unsigned* __restrict__ wvh) {
  int ep = blockIdx.x;      // 0..31 (e-pair)
  int od = threadIdx.x;     // 0..255 : h*64+d
  int h = od >> 6, d = od & 63;
  int e0 = ep * 2;
  float s0 = 0.f, s1 = 0.f;
#pragma unroll 4
  for (int k = 0; k < 64; ++k) {
    float wk = WK[(h * 64 + k) * 64 + d];
    s0 += WQ[(h * 64 + k) * 64 + e0] * wk;
    s1 += WQ[(h * 64 + k) * 64 + e0 + 1] * wk;
  }
  // B-frag quad order: one uint4 = eps {eq*4+0..3} for a fixed od
  AhTs[((ep >> 2) * 256 + od) * 4 + (ep & 3)] = pk2(s0 * 0.125f, s1 * 0.125f);
  if (ep == 0) {
    float r = 0.f;
    for (int k = 0; k < 64; ++k) r += WQb[h * 64 + k] * WK[(h * 64 + k) * 64 + d];
    rbar[od] = r * 0.125f;
    if (od < 128) {   // wvh[i][h][jp]
      int i = od >> 4, hh = (od >> 2) & 3, jp = od & 3;
      float w0 = 0.f, w1 = 0.f;
      for (int b = 0; b < 6; ++b) {
        w0 += coeffs[hh * 6 + b] * bases[b * 64 + i * 8 + 2 * jp];
        w1 += coeffs[hh * 6 + b] * bases[b * 64 + i * 8 + 2 * jp + 1];
      }
      wvh[od] = pk2(w0, w1);
    }
  }
}

// x (f32) -> xh (packed f16x2), vectorized: 8 floats -> 1 uint4 per thread
__global__ void xconv_kernel(const float* __restrict__ x, unsigned* __restrict__ xh) {
  int idx = blockIdx.x * 256 + threadIdx.x;   // uint4 index, 0 .. NV*8-1
  if (idx < NV * 8) {
    float4 a = ((const float4*)x)[idx * 2];
    float4 b = ((const float4*)x)[idx * 2 + 1];
    uint4 o;
    o.x = pk2(a.x, a.y);
    o.y = pk2(a.z, a.w);
    o.z = pk2(b.x, b.y);
    o.w = pk2(b.z, b.w);
    ((uint4*)xh)[idx] = o;
  }
}

__device__ __forceinline__ void gload_lds16(const void* g, void* l) {
  __builtin_amdgcn_global_load_lds((const __attribute__((address_space(1))) void*)g,
                                   (__attribute__((address_space(3))) void*)l, 16, 0, 0);
}

// ---------------- attention: 1 wave = 1 vertex; MFMA q~ + MFMA scores (verified 84us front)
// + in-register softmax and g via mfma 16x16x16f16 (verified round-2 back) ----------------
__global__ __launch_bounds__(256, 5) void attn_kernel(
    const unsigned* __restrict__ xh, const int* __restrict__ nbr,
    const float* __restrict__ P, const unsigned* __restrict__ AhTs,
    const float* __restrict__ rbar, const unsigned* __restrict__ wvh,
    float* __restrict__ out) {
  __shared__ __align__(16) _Float16 Ph[4][1024];     // 8 KB   f16 P [m*8+o rows of 8 h2]
  __shared__ __align__(16) _Float16 Xd[4][1024];     // 8 KB   f16 X rows [m][64]
  __shared__ __align__(16) _Float16 q16[4][256];     // 2 KB   [vi][h*64+d] (q~+rbar, f16)
  __shared__ __align__(16) _Float16 Ftr[4][1152];    // 9 KB   [m][72-stride] f16 (DEDICATED)
  __shared__ __align__(16) _Float16 g16[4][4][64];   // 2 KB   [w][h][d]  -> 29 KB total

  const int t = threadIdx.x;
  const int w = t >> 6, lane = t & 63;
  const int v0 = blockIdx.x * 4;
  const int v = v0 + w;    // this wave's vertex
  const int o = lane >> 3, p = lane & 7;
  const int c_ep = lane >> 3, i_ep = lane & 7;
  const char* xhb = (const char*)xh;

  // ---- neighbor indices in X-DMA lane layout ----
  int nbi0 = nbr[(size_t)v * 16 + (lane >> 3)];        // rows 0..7
  int nbi1 = nbr[(size_t)v * 16 + 8 + (lane >> 3)];    // rows 8..15

  // ---- P reg-staged load: lane owns 16 consecutive f32 (coalesced) ----
  uint4 c0, c1, c2, c3;
  {
    const uint4* Pg = (const uint4*)(P + (size_t)v * 1024);
    c0 = Pg[lane * 4 + 0];
    c1 = Pg[lane * 4 + 1];
    c2 = Pg[lane * 4 + 2];
    c3 = Pg[lane * 4 + 3];
  }

  // ---- X DMA (2 x 1KB, f16: 8 rows per instr) ----
  gload_lds16(xhb + (size_t)nbi0 * 128 + (lane & 7) * 16, &Xd[w][0]);
  gload_lds16(xhb + (size_t)nbi1 * 128 + (lane & 7) * 16, &Xd[w][512]);

  // ---- rbar for q16 write (writer lanes<16; od = w*64 + tt*16 + lane) ----
  float rbq[4];
#pragma unroll
  for (int tt = 0; tt < 4; ++tt) rbq[tt] = rbar[w * 64 + tt * 16 + (lane & 15)];

  // ---- q~ via MFMA: C[vi][od] = sum_e x[v0+vi][e] A~[e][od] ----
  {
    const int od0 = w * 64;
    const uint4* xrow4 = (const uint4*)(xh + (size_t)(v0 + (lane & 3)) * 32);
    f16x8 afrag0 = u4h8(xrow4[(lane >> 4)]);       // K-step 0: e 0..31
    f16x8 afrag1 = u4h8(xrow4[4 + (lane >> 4)]);   // K-step 1: e 32..63

    f32x4 acc[4];
#pragma unroll
    for (int tt = 0; tt < 4; ++tt) acc[tt] = (f32x4){0.f, 0.f, 0.f, 0.f};

#pragma unroll
    for (int tt = 0; tt < 4; ++tt) {
      const int colbase = od0 + tt * 16 + (lane & 15);
#pragma unroll
      for (int s = 0; s < 2; ++s) {
        // B frag: one dwordx4 in quad-swizzled layout (eq = s*4 + (lane>>4))
        uint4 bu = *(const uint4*)&AhTs[((s * 4 + (lane >> 4)) * 256 + colbase) * 4];
        acc[tt] = __builtin_amdgcn_mfma_f32_16x16x32_f16(s ? afrag1 : afrag0, u4h8(bu),
                                                         acc[tt], 0, 0, 0);
      }
    }
    // C: col = lane&15, row = (lane>>4)*4 + reg ; rows 0..3 = vertices, lanes 0..15
    if (lane < 16) {
#pragma unroll
      for (int tt = 0; tt < 4; ++tt)
#pragma unroll
        for (int vi = 0; vi < 4; ++vi)
          q16[vi][od0 + tt * 16 + lane] = (_Float16)(acc[tt][vi] + rbq[tt]);
    }
  }
  __syncthreads();   // HW barrier: drains VMEM (P regs + X DMA) and publishes q16

  // ---- hoisted scores B-frags (q16 stable from here) ----
  const int hb = (lane & 15) & 3;   // cols 4..15 duplicate h 0..3; outputs unused
  f16x8 bq0 = u4h8(*(const uint4*)&q16[w][hb * 64 + (lane >> 4) * 8]);
  f16x8 bq1 = u4h8(*(const uint4*)&q16[w][hb * 64 + 32 + (lane >> 4) * 8]);

  // ---- convert P f32->f16 in-register, write to Ph (2 x ds_write_b128) ----
  {
    uint4 w0, w1;
    w0.x = pk2(__uint_as_float(c0.x), __uint_as_float(c0.y));
    w0.y = pk2(__uint_as_float(c0.z), __uint_as_float(c0.w));
    w0.z = pk2(__uint_as_float(c1.x), __uint_as_float(c1.y));
    w0.w = pk2(__uint_as_float(c1.z), __uint_as_float(c1.w));
    w1.x = pk2(__uint_as_float(c2.x), __uint_as_float(c2.y));
    w1.y = pk2(__uint_as_float(c2.z), __uint_as_float(c2.w));
    w1.z = pk2(__uint_as_float(c3.x), __uint_as_float(c3.y));
    w1.w = pk2(__uint_as_float(c3.z), __uint_as_float(c3.w));
    *(uint4*)&Ph[w][lane * 16] = w0;
    *(uint4*)&Ph[w][lane * 16 + 8] = w1;
  }
  lds_fence();

  // ---- f' : lane = d = o*8+p ; P16 row (m*8+o), X16 row (m*8+p) ----
  const uint4* P16 = (const uint4*)&Ph[w][0];
  const uint4* X16 = (const uint4*)&Xd[w][0];
  float freg[16];
#pragma unroll
  for (int m = 0; m < 16; ++m) {
    uint4 Pu = P16[m * 8 + o];
    uint4 Xu = X16[m * 8 + p];
    freg[m] = fdot2f(u2h(Pu.x), u2h(Xu.x),
              fdot2f(u2h(Pu.y), u2h(Xu.y),
              fdot2f(u2h(Pu.z), u2h(Xu.z),
              fdot2f(u2h(Pu.w), u2h(Xu.w), 0.f))));
  }
  lds_fence();

  // ---- transpose F to A-frag layout: Ftr[m][d], stride 72 f16 (144 B) ----
#pragma unroll
  for (int m = 0; m < 16; ++m) Ftr[w][m * 72 + lane] = (_Float16)freg[m];
  lds_fence();   // essential: Ftr writes visible before reads

  // ---- scores via MFMA: S[m][h] = sum_d F[m][d] q16[h][d] ----
  f32x4 sac = (f32x4){0.f, 0.f, 0.f, 0.f};
  {
    f16x8 af0 = u4h8(*(const uint4*)&Ftr[w][(lane & 15) * 72 + (lane >> 4) * 8]);
    f16x8 af1 = u4h8(*(const uint4*)&Ftr[w][(lane & 15) * 72 + 32 + (lane >> 4) * 8]);
    sac = __builtin_amdgcn_mfma_f32_16x16x32_f16(af0, bq0, sac, 0, 0, 0);
    sac = __builtin_amdgcn_mfma_f32_16x16x32_f16(af1, bq1, sac, 0, 0, 0);
    // lane holds S[m=(lane>>4)*4+r][h=lane&15], r=0..3 (h<4 meaningful)
  }

  // ---- softmax fully in-register: eb = exp(S)/sum -> g-MFMA B-frag (k=m order) ----
  f16x4 eb;
  {
    float e0 = __expf(sac[0]), e1 = __expf(sac[1]);
    float e2 = __expf(sac[2]), e3 = __expf(sac[3]);
    float pp = (e0 + e1) + (e2 + e3);
    pp += __shfl_xor(pp, 16);
    pp += __shfl_xor(pp, 32);
    float is = __builtin_amdgcn_rcpf(pp);
    uint2 eu;
    eu.x = pk2(e0 * is, e1 * is);
    eu.y = pk2(e2 * is, e3 * is);
    eb = u2h4(eu);
  }

  // ---- epilogue weights (late load, overlaps g compute) ----
  uint4 wq[4];
#pragma unroll
  for (int h = 0; h < 4; ++h) wq[h] = *(const uint4*)&wvh[i_ep * 16 + h * 4];

  // ---- g via 4x mfma 16x16x16f16: g[h][d] = sum_m eb[m][h] F[m][d] ----
  {
    const int rl = lane & 15, kg = lane >> 4;
#pragma unroll
    for (int b2 = 0; b2 < 4; ++b2) {
      f16x4 ga;
#pragma unroll
      for (int tt = 0; tt < 4; ++tt)
        ga[tt] = Ftr[w][(kg * 4 + tt) * 72 + b2 * 16 + rl];  // A[i=rl][k=kg*4+tt]
      f32x4 zg = (f32x4){0.f, 0.f, 0.f, 0.f};
      f32x4 gacc = __builtin_amdgcn_mfma_f32_16x16x16f16(ga, eb, zg, 0, 0, 0);
      // D[row=kg*4+reg][col=h'=rl]: g[h'][b2*16 + kg*4 + reg], h'<4 useful
      if (rl < 4) {
        uint2 gv;
        gv.x = pk2(gacc[0], gacc[1]);
        gv.y = pk2(gacc[2], gacc[3]);
        *(uint2*)&g16[w][rl][b2 * 16 + kg * 4] = gv;
      }
    }
  }
  lds_fence();

  // ---- W_V epilogue (unchanged) ----
#pragma unroll
  for (int h = 0; h < 4; ++h) {
    uint4 gq = *(const uint4*)&g16[w][h][c_ep * 8];
    float oacc = fdot2f(u2h(wq[h].x), u2h(gq.x),
                 fdot2f(u2h(wq[h].y), u2h(gq.y),
                 fdot2f(u2h(wq[h].z), u2h(gq.z),
                 fdot2f(u2h(wq[h].w), u2h(gq.w), 0.f))));
    out[(size_t)v * 256 + h * 64 + lane] = oacc;
  }
}

extern "C" void kernel_launch(void* const* d_in, const int* in_sizes, int n_in,
                              void* d_out, int out_size, void* d_ws, size_t ws_size,
                              hipStream_t stream) {
  const float* x      = (const float*)d_in[0];
  const int*   nbr    = (const int*)d_in[1];
  const float* P      = (const float*)d_in[2];
  // d_in[3] = rel_pos_u : unused by the reference
  const float* WQ     = (const float*)d_in[4];
  const float* WQb    = (const float*)d_in[5];
  const float* WK     = (const float*)d_in[6];
  // d_in[7] = W_K_b : softmax-invariant -> dropped
  const float* bases  = (const float*)d_in[8];
  const float* coeffs = (const float*)d_in[9];

  unsigned* AhTs = (unsigned*)d_ws;
  float* rbar   = (float*)((char*)d_ws + 32768);
  unsigned* wvh = (unsigned*)((char*)d_ws + 33792);
  unsigned* xh  = (unsigned*)((char*)d_ws + 34816);
  float* out    = (float*)d_out;

  hipLaunchKernelGGL(setup_kernel, dim3(32), dim3(256), 0, stream,
                     WQ, WQb, WK, bases, coeffs, AhTs, rbar, wvh);
  hipLaunchKernelGGL(xconv_kernel, dim3((NV * 8 + 255) / 256), dim3(256), 0, stream, x, xh);
  hipLaunchKernelGGL(attn_kernel, dim3(NV / 4), dim3(256), 0, stream,
                     xh, nbr, P, AhTs, rbar, wvh, out);
}

// Round 4
// 85.113 us; speedup vs baseline: 1.0581x; 1.0208x over previous
//
#include <hip/hip_runtime.h>
#include <hip/hip_bf16.h>

#define NV 50000

// ws layout:
//   [0, 32768)        AhTs packed f16x2, B-frag quad order: [eq=ep>>2][od][r=ep&3]
//   [32768, 33792)    rbar f32 [256]
//   [33792, 34304)    wvh  packed f16x2 [8 i][4 h][4 jp] (W_V)
//   [34816, +6.4MB)   xh   packed f16x2 [NV][32]         (x converted)

typedef _Float16 h2_t __attribute__((ext_vector_type(2)));
typedef _Float16 f16x8 __attribute__((ext_vector_type(8)));
typedef float f32x4 __attribute__((ext_vector_type(4)));

#if defined(__has_builtin)
#if __has_builtin(__builtin_amdgcn_fdot2)
#define HAVE_FDOT2 1
#endif
#endif

__device__ __forceinline__ float fdot2f(h2_t a, h2_t b, float c) {
#ifdef HAVE_FDOT2
  return __builtin_amdgcn_fdot2(a, b, c, false);
#else
  return fmaf((float)a.x, (float)b.x, fmaf((float)a.y, (float)b.y, c));
#endif
}
__device__ __forceinline__ h2_t u2h(unsigned u) {
  union { unsigned u; h2_t h; } c; c.u = u; return c.h;
}
__device__ __forceinline__ unsigned pk2(float a, float b) {
  auto v = __builtin_amdgcn_cvt_pkrtz(a, b);   // __fp16 ext_vector(2)
  union { decltype(v) h; unsigned u; } c; c.h = v; return c.u;
}
__device__ __forceinline__ f16x8 u4h8(uint4 u) {
  union { uint4 u; f16x8 h; } c; c.u = u; return c.h;
}
// IR-level memory clobber + HW LDS drain + scheduler pin (rule #18)
__device__ __forceinline__ void lds_fence() {
  asm volatile("s_waitcnt lgkmcnt(0)" ::: "memory");
  __builtin_amdgcn_sched_barrier(0);
}

__global__ void setup_kernel(const float* __restrict__ WQ, const float* __restrict__ WQb,
                             const float* __restrict__ WK,
                             const float* __restrict__ bases, const float* __restrict__ coeffs,
                             unsigned* __restrict__ AhTs, float* __restrict__ rbar,
                             unsigned* __restrict__ wvh) {
  int ep = blockIdx.x;      // 0..31 (e-pair)
  int od = threadIdx.x;     // 0..255 : h*64+d
  int h = od >> 6, d = od & 63;
  int e0 = ep * 2;
  float s0 = 0.f, s1 = 0.f;
#pragma unroll 4
  for (int k = 0; k < 64; ++k) {
    float wk = WK[(h * 64 + k) * 64 + d];
    s0 += WQ[(h * 64 + k) * 64 + e0] * wk;
    s1 += WQ[(h * 64 + k) * 64 + e0 + 1] * wk;
  }
  // B-frag quad order: one uint4 = eps {eq*4+0..3} for a fixed od
  AhTs[((ep >> 2) * 256 + od) * 4 + (ep & 3)] = pk2(s0 * 0.125f, s1 * 0.125f);
  if (ep == 0) {
    float r = 0.f;
    for (int k = 0; k < 64; ++k) r += WQb[h * 64 + k] * WK[(h * 64 + k) * 64 + d];
    rbar[od] = r * 0.125f;
    if (od < 128) {   // wvh[i][h][jp]
      int i = od >> 4, hh = (od >> 2) & 3, jp = od & 3;
      float w0 = 0.f, w1 = 0.f;
      for (int b = 0; b < 6; ++b) {
        w0 += coeffs[hh * 6 + b] * bases[b * 64 + i * 8 + 2 * jp];
        w1 += coeffs[hh * 6 + b] * bases[b * 64 + i * 8 + 2 * jp + 1];
      }
      wvh[od] = pk2(w0, w1);
    }
  }
}

// x (f32) -> xh (packed f16x2), vectorized: 8 floats -> 1 uint4 per thread
__global__ void xconv_kernel(const float* __restrict__ x, unsigned* __restrict__ xh) {
  int idx = blockIdx.x * 256 + threadIdx.x;   // uint4 index, 0 .. NV*8-1
  if (idx < NV * 8) {
    float4 a = ((const float4*)x)[idx * 2];
    float4 b = ((const float4*)x)[idx * 2 + 1];
    uint4 o;
    o.x = pk2(a.x, a.y);
    o.y = pk2(a.z, a.w);
    o.z = pk2(b.x, b.y);
    o.w = pk2(b.z, b.w);
    ((uint4*)xh)[idx] = o;
  }
}

__device__ __forceinline__ void gload_lds16(const void* g, void* l) {
  __builtin_amdgcn_global_load_lds((const __attribute__((address_space(1))) void*)g,
                                   (__attribute__((address_space(3))) void*)l, 16, 0, 0);
}

// ---------------- attention: 1 wave = 1 vertex (R0 structure, 84.2us) with:
//  - Ftr aliased onto dead Ph+Xd region  (LDS 30 -> 21 KB)
//  - __launch_bounds__(256,6)            (5 -> 6 blocks/CU)
//  - P convert + Ph write hoisted pre-barrier (c0..c3 retire before q~ MFMA) ----------------
__global__ __launch_bounds__(256, 6) void attn_kernel(
    const unsigned* __restrict__ xh, const int* __restrict__ nbr,
    const float* __restrict__ P, const unsigned* __restrict__ AhTs,
    const float* __restrict__ rbar, const unsigned* __restrict__ wvh,
    float* __restrict__ out) {
  // per-wave 4KB union: phase A = Ph[0:1024] + Xd[1024:2048] (f16 idx);
  //                     phase B = Ftr[0:1152] stride-72 (overwrites after f' fence)
  __shared__ __align__(16) _Float16 UN[4][2048];     // 16 KB
  __shared__ __align__(16) _Float16 q16[4][256];     // 2 KB   [vi][h*64+d] (q~+rbar, f16)
  __shared__ __align__(16) float    attn_lds[4][64]; // 1 KB   [m*4+h] unnormalized exp
  __shared__ __align__(16) _Float16 g16[4][4][64];   // 2 KB   [w][h][d]  -> 21 KB total

  const int t = threadIdx.x;
  const int w = t >> 6, lane = t & 63;
  const int v0 = blockIdx.x * 4;
  const int v = v0 + w;    // this wave's vertex
  const int o = lane >> 3, p = lane & 7;
  const int c_ep = lane >> 3, i_ep = lane & 7;
  const char* xhb = (const char*)xh;

  // ---- neighbor indices in X-DMA lane layout ----
  int nbi0 = nbr[(size_t)v * 16 + (lane >> 3)];        // rows 0..7
  int nbi1 = nbr[(size_t)v * 16 + 8 + (lane >> 3)];    // rows 8..15

  // ---- P reg-staged load: lane owns 16 consecutive f32 (coalesced) ----
  uint4 c0, c1, c2, c3;
  {
    const uint4* Pg = (const uint4*)(P + (size_t)v * 1024);
    c0 = Pg[lane * 4 + 0];
    c1 = Pg[lane * 4 + 1];
    c2 = Pg[lane * 4 + 2];
    c3 = Pg[lane * 4 + 3];
  }

  // ---- X DMA (2 x 1KB, f16: 8 rows per instr) into Xd = UN[w][1024..] ----
  gload_lds16(xhb + (size_t)nbi0 * 128 + (lane & 7) * 16, &UN[w][1024]);
  gload_lds16(xhb + (size_t)nbi1 * 128 + (lane & 7) * 16, &UN[w][1536]);

  // ---- rbar for q16 write (writer lanes<16; od = w*64 + tt*16 + lane) ----
  float rbq[4];
#pragma unroll
  for (int tt = 0; tt < 4; ++tt) rbq[tt] = rbar[w * 64 + tt * 16 + (lane & 15)];

  // ---- convert P f32->f16 EARLY, write Ph (retires c0..c3 before MFMA phase) ----
  {
    uint4 w0, w1;
    w0.x = pk2(__uint_as_float(c0.x), __uint_as_float(c0.y));
    w0.y = pk2(__uint_as_float(c0.z), __uint_as_float(c0.w));
    w0.z = pk2(__uint_as_float(c1.x), __uint_as_float(c1.y));
    w0.w = pk2(__uint_as_float(c1.z), __uint_as_float(c1.w));
    w1.x = pk2(__uint_as_float(c2.x), __uint_as_float(c2.y));
    w1.y = pk2(__uint_as_float(c2.z), __uint_as_float(c2.w));
    w1.z = pk2(__uint_as_float(c3.x), __uint_as_float(c3.y));
    w1.w = pk2(__uint_as_float(c3.z), __uint_as_float(c3.w));
    *(uint4*)&UN[w][lane * 16] = w0;
    *(uint4*)&UN[w][lane * 16 + 8] = w1;
  }

  // ---- q~ via MFMA: C[vi][od] = sum_e x[v0+vi][e] A~[e][od] ----
  {
    const int od0 = w * 64;
    const uint4* xrow4 = (const uint4*)(xh + (size_t)(v0 + (lane & 3)) * 32);
    f16x8 afrag0 = u4h8(xrow4[(lane >> 4)]);       // K-step 0: e 0..31
    f16x8 afrag1 = u4h8(xrow4[4 + (lane >> 4)]);   // K-step 1: e 32..63

    f32x4 acc[4];
#pragma unroll
    for (int tt = 0; tt < 4; ++tt) acc[tt] = (f32x4){0.f, 0.f, 0.f, 0.f};

#pragma unroll
    for (int tt = 0; tt < 4; ++tt) {
      const int colbase = od0 + tt * 16 + (lane & 15);
#pragma unroll
      for (int s = 0; s < 2; ++s) {
        // B frag: one dwordx4 in quad-swizzled layout (eq = s*4 + (lane>>4))
        uint4 bu = *(const uint4*)&AhTs[((s * 4 + (lane >> 4)) * 256 + colbase) * 4];
        acc[tt] = __builtin_amdgcn_mfma_f32_16x16x32_f16(s ? afrag1 : afrag0, u4h8(bu),
                                                         acc[tt], 0, 0, 0);
      }
    }
    // C: col = lane&15, row = (lane>>4)*4 + reg ; rows 0..3 = vertices, lanes 0..15
    if (lane < 16) {
#pragma unroll
      for (int tt = 0; tt < 4; ++tt)
#pragma unroll
        for (int vi = 0; vi < 4; ++vi)
          q16[vi][od0 + tt * 16 + lane] = (_Float16)(acc[tt][vi] + rbq[tt]);
    }
  }
  __syncthreads();   // drains VMEM (X DMA) + LDS (Ph, q16); publishes q16 across waves

  // ---- hoisted scores B-frags (q16 stable from here) ----
  const int hb = (lane & 15) & 3;   // cols 4..15 duplicate h 0..3; outputs unused
  f16x8 bq0 = u4h8(*(const uint4*)&q16[w][hb * 64 + (lane >> 4) * 8]);
  f16x8 bq1 = u4h8(*(const uint4*)&q16[w][hb * 64 + 32 + (lane >> 4) * 8]);

  // ---- f' : lane = d = o*8+p ; P16 row (m*8+o), X16 row (m*8+p) ----
  const uint4* P16 = (const uint4*)&UN[w][0];
  const uint4* X16 = (const uint4*)&UN[w][1024];
  float freg[16];
#pragma unroll
  for (int m = 0; m < 16; ++m) {
    uint4 Pu = P16[m * 8 + o];
    uint4 Xu = X16[m * 8 + p];
    freg[m] = fdot2f(u2h(Pu.x), u2h(Xu.x),
              fdot2f(u2h(Pu.y), u2h(Xu.y),
              fdot2f(u2h(Pu.z), u2h(Xu.z),
              fdot2f(u2h(Pu.w), u2h(Xu.w), 0.f))));
  }
  lds_fence();   // REQUIRED: Ph/Xd reads must retire before Ftr overwrites the union

  // ---- transpose F to A-frag layout: Ftr[m][d] = UN[w][m*72+d] (aliases Ph/Xd) ----
#pragma unroll
  for (int m = 0; m < 16; ++m) UN[w][m * 72 + lane] = (_Float16)freg[m];
  lds_fence();   // Ftr writes visible before reads

  // ---- scores via MFMA: S[m][h] = sum_d F[m][d] q16[h][d] ----
  f32x4 sac = (f32x4){0.f, 0.f, 0.f, 0.f};
  {
    f16x8 af0 = u4h8(*(const uint4*)&UN[w][(lane & 15) * 72 + (lane >> 4) * 8]);
    f16x8 af1 = u4h8(*(const uint4*)&UN[w][(lane & 15) * 72 + 32 + (lane >> 4) * 8]);
    sac = __builtin_amdgcn_mfma_f32_16x16x32_f16(af0, bq0, sac, 0, 0, 0);
    sac = __builtin_amdgcn_mfma_f32_16x16x32_f16(af1, bq1, sac, 0, 0, 0);
    // lane holds S[m=(lane>>4)*4+r][h=lane&15], r=0..3 (h<4 meaningful)
  }

  // ---- no-max softmax: raw exp, normalization deferred to g (|s| << 88) ----
  {
    float e0 = __expf(sac[0]), e1 = __expf(sac[1]);
    float e2 = __expf(sac[2]), e3 = __expf(sac[3]);
    if ((lane & 15) < 4) {
      const int h = lane & 15, mb = (lane >> 4) * 4;
      attn_lds[w][(mb + 0) * 4 + h] = e0;
      attn_lds[w][(mb + 1) * 4 + h] = e1;
      attn_lds[w][(mb + 2) * 4 + h] = e2;
      attn_lds[w][(mb + 3) * 4 + h] = e3;
    }
  }
  lds_fence();

  // ---- epilogue weights (late load, overlaps g compute) ----
  uint4 wq[4];
#pragma unroll
  for (int h = 0; h < 4; ++h) wq[h] = *(const uint4*)&wvh[i_ep * 16 + h * 4];

  // ---- g[h][d] = (sum_m e[m][h] f'[m][d]) / (sum_m e[m][h]) ; lane = d ----
  float g[4] = {0.f, 0.f, 0.f, 0.f};
  float s4[4] = {0.f, 0.f, 0.f, 0.f};
#pragma unroll
  for (int m = 0; m < 16; ++m) {
    float4 a4 = *(const float4*)&attn_lds[w][m * 4];   // broadcast read
    g[0] = fmaf(a4.x, freg[m], g[0]);
    g[1] = fmaf(a4.y, freg[m], g[1]);
    g[2] = fmaf(a4.z, freg[m], g[2]);
    g[3] = fmaf(a4.w, freg[m], g[3]);
    s4[0] += a4.x; s4[1] += a4.y; s4[2] += a4.z; s4[3] += a4.w;
  }

  // ---- W_V epilogue via f16 tile + dot2 (normalize folded into the f16 cast) ----
#pragma unroll
  for (int h = 0; h < 4; ++h) g16[w][h][lane] = (_Float16)(g[h] / s4[h]);
  lds_fence();
#pragma unroll
  for (int h = 0; h < 4; ++h) {
    uint4 gq = *(const uint4*)&g16[w][h][c_ep * 8];
    float oacc = fdot2f(u2h(wq[h].x), u2h(gq.x),
                 fdot2f(u2h(wq[h].y), u2h(gq.y),
                 fdot2f(u2h(wq[h].z), u2h(gq.z),
                 fdot2f(u2h(wq[h].w), u2h(gq.w), 0.f))));
    out[(size_t)v * 256 + h * 64 + lane] = oacc;
  }
}

extern "C" void kernel_launch(void* const* d_in, const int* in_sizes, int n_in,
                              void* d_out, int out_size, void* d_ws, size_t ws_size,
                              hipStream_t stream) {
  const float* x      = (const float*)d_in[0];
  const int*   nbr    = (const int*)d_in[1];
  const float* P      = (const float*)d_in[2];
  // d_in[3] = rel_pos_u : unused by the reference
  const float* WQ     = (const float*)d_in[4];
  const float* WQb    = (const float*)d_in[5];
  const float* WK     = (const float*)d_in[6];
  // d_in[7] = W_K_b : softmax-invariant -> dropped
  const float* bases  = (const float*)d_in[8];
  const float* coeffs = (const float*)d_in[9];

  unsigned* AhTs = (unsigned*)d_ws;
  float* rbar   = (float*)((char*)d_ws + 32768);
  unsigned* wvh = (unsigned*)((char*)d_ws + 33792);
  unsigned* xh  = (unsigned*)((char*)d_ws + 34816);
  float* out    = (float*)d_out;

  hipLaunchKernelGGL(setup_kernel, dim3(32), dim3(256), 0, stream,
                     WQ, WQb, WK, bases, coeffs, AhTs, rbar, wvh);
  hipLaunchKernelGGL(xconv_kernel, dim3((NV * 8 + 255) / 256), dim3(256), 0, stream, x, xh);
  hipLaunchKernelGGL(attn_kernel, dim3(NV / 4), dim3(256), 0, stream,
                     xh, nbr, P, AhTs, rbar, wvh, out);
}

// Round 5
// 81.604 us; speedup vs baseline: 1.1036x; 1.0430x over previous
//
#include <hip/hip_runtime.h>
#include <hip/hip_bf16.h>

#define NV 50000

// ws layout:
//   [0, 32768)        AhTs packed f16x2, B-frag quad order: [eq=ep>>2][od][r=ep&3]
//   [32768, 33792)    rbar f32 [256]
//   [33792, 34304)    wvh  packed f16x2 [8 i][4 h][4 jp] (W_V)
//   [34816, +6.4MB)   xh   packed f16x2 [NV][32]         (x converted)

typedef _Float16 h2_t __attribute__((ext_vector_type(2)));
typedef _Float16 f16x8 __attribute__((ext_vector_type(8)));
typedef float f32x4 __attribute__((ext_vector_type(4)));
typedef unsigned u32x4 __attribute__((ext_vector_type(4)));

#if defined(__has_builtin)
#if __has_builtin(__builtin_amdgcn_fdot2)
#define HAVE_FDOT2 1
#endif
#endif

__device__ __forceinline__ float fdot2f(h2_t a, h2_t b, float c) {
#ifdef HAVE_FDOT2
  return __builtin_amdgcn_fdot2(a, b, c, false);
#else
  return fmaf((float)a.x, (float)b.x, fmaf((float)a.y, (float)b.y, c));
#endif
}
__device__ __forceinline__ h2_t u2h(unsigned u) {
  union { unsigned u; h2_t h; } c; c.u = u; return c.h;
}
__device__ __forceinline__ unsigned pk2(float a, float b) {
  auto v = __builtin_amdgcn_cvt_pkrtz(a, b);   // __fp16 ext_vector(2)
  union { decltype(v) h; unsigned u; } c; c.h = v; return c.u;
}
__device__ __forceinline__ f16x8 u4h8(uint4 u) {
  union { uint4 u; f16x8 h; } c; c.u = u; return c.h;
}
// IR-level memory clobber + HW LDS drain + scheduler pin (rule #18)
__device__ __forceinline__ void lds_fence() {
  asm volatile("s_waitcnt lgkmcnt(0)" ::: "memory");
  __builtin_amdgcn_sched_barrier(0);
}

// setup (blocks 0..31) + xconv (blocks 32..) fused: one launch
__global__ void prep_kernel(const float* __restrict__ WQ, const float* __restrict__ WQb,
                            const float* __restrict__ WK,
                            const float* __restrict__ bases, const float* __restrict__ coeffs,
                            const float* __restrict__ x,
                            unsigned* __restrict__ AhTs, float* __restrict__ rbar,
                            unsigned* __restrict__ wvh, unsigned* __restrict__ xh) {
  if (blockIdx.x < 32) {
    int ep = blockIdx.x;      // 0..31 (e-pair)
    int od = threadIdx.x;     // 0..255 : h*64+d
    int h = od >> 6, d = od & 63;
    int e0 = ep * 2;
    float s0 = 0.f, s1 = 0.f;
#pragma unroll 4
    for (int k = 0; k < 64; ++k) {
      float wk = WK[(h * 64 + k) * 64 + d];
      s0 += WQ[(h * 64 + k) * 64 + e0] * wk;
      s1 += WQ[(h * 64 + k) * 64 + e0 + 1] * wk;
    }
    // B-frag quad order: one uint4 = eps {eq*4+0..3} for a fixed od
    AhTs[((ep >> 2) * 256 + od) * 4 + (ep & 3)] = pk2(s0 * 0.125f, s1 * 0.125f);
    if (ep == 0) {
      float r = 0.f;
      for (int k = 0; k < 64; ++k) r += WQb[h * 64 + k] * WK[(h * 64 + k) * 64 + d];
      rbar[od] = r * 0.125f;
      if (od < 128) {   // wvh[i][h][jp]
        int i = od >> 4, hh = (od >> 2) & 3, jp = od & 3;
        float w0 = 0.f, w1 = 0.f;
        for (int b = 0; b < 6; ++b) {
          w0 += coeffs[hh * 6 + b] * bases[b * 64 + i * 8 + 2 * jp];
          w1 += coeffs[hh * 6 + b] * bases[b * 64 + i * 8 + 2 * jp + 1];
        }
        wvh[od] = pk2(w0, w1);
      }
    }
  } else {
    int idx = (blockIdx.x - 32) * 256 + threadIdx.x;   // uint4 index, 0 .. NV*8-1
    if (idx < NV * 8) {
      float4 a = ((const float4*)x)[idx * 2];
      float4 b = ((const float4*)x)[idx * 2 + 1];
      uint4 o;
      o.x = pk2(a.x, a.y);
      o.y = pk2(a.z, a.w);
      o.z = pk2(b.x, b.y);
      o.w = pk2(b.z, b.w);
      ((uint4*)xh)[idx] = o;
    }
  }
}

__device__ __forceinline__ void gload_lds16(const void* g, void* l) {
  __builtin_amdgcn_global_load_lds((const __attribute__((address_space(1))) void*)g,
                                   (__attribute__((address_space(3))) void*)l, 16, 0, 0);
}

// ---------------- attention: 1 wave = 1 vertex (R4 structure) with:
//  - COALESCED P load: instr k reads a contiguous 1KB slab (16 lines/instr, was 64)
//  - non-temporal P loads + out stores (protect 6.4MB xh gather table in L2)
//  - Ftr aliased onto dead Ph+Xd region (21 KB LDS), __launch_bounds__(256,6) ----------------
__global__ __launch_bounds__(256, 6) void attn_kernel(
    const unsigned* __restrict__ xh, const int* __restrict__ nbr,
    const float* __restrict__ P, const unsigned* __restrict__ AhTs,
    const float* __restrict__ rbar, const unsigned* __restrict__ wvh,
    float* __restrict__ out) {
  // per-wave 4KB union: phase A = Ph[0:1024] + Xd[1024:2048] (f16 idx);
  //                     phase B = Ftr[0:1152] stride-72 (overwrites after f' fence)
  __shared__ __align__(16) _Float16 UN[4][2048];     // 16 KB
  __shared__ __align__(16) _Float16 q16[4][256];     // 2 KB   [vi][h*64+d] (q~+rbar, f16)
  __shared__ __align__(16) float    attn_lds[4][64]; // 1 KB   [m*4+h] unnormalized exp
  __shared__ __align__(16) _Float16 g16[4][4][64];   // 2 KB   [w][h][d]  -> 21 KB total

  const int t = threadIdx.x;
  const int w = t >> 6, lane = t & 63;
  const int v0 = blockIdx.x * 4;
  const int v = v0 + w;    // this wave's vertex
  const int o = lane >> 3, p = lane & 7;
  const int c_ep = lane >> 3, i_ep = lane & 7;
  const char* xhb = (const char*)xh;

  // ---- neighbor indices in X-DMA lane layout ----
  int nbi0 = nbr[(size_t)v * 16 + (lane >> 3)];        // rows 0..7
  int nbi1 = nbr[(size_t)v * 16 + 8 + (lane >> 3)];    // rows 8..15

  // ---- P load, COALESCED + non-temporal: instr k = contiguous 1KB slab ----
  u32x4 c0, c1, c2, c3;
  {
    const u32x4* Pg = (const u32x4*)(P + (size_t)v * 1024);
    c0 = __builtin_nontemporal_load(Pg + lane);          // f32 idx lane*4 .. +3
    c1 = __builtin_nontemporal_load(Pg + 64 + lane);     // + 256
    c2 = __builtin_nontemporal_load(Pg + 128 + lane);    // + 512
    c3 = __builtin_nontemporal_load(Pg + 192 + lane);    // + 768
  }

  // ---- X DMA (2 x 1KB, f16: 8 rows per instr) into Xd = UN[w][1024..] ----
  gload_lds16(xhb + (size_t)nbi0 * 128 + (lane & 7) * 16, &UN[w][1024]);
  gload_lds16(xhb + (size_t)nbi1 * 128 + (lane & 7) * 16, &UN[w][1536]);

  // ---- rbar for q16 write (writer lanes<16; od = w*64 + tt*16 + lane) ----
  float rbq[4];
#pragma unroll
  for (int tt = 0; tt < 4; ++tt) rbq[tt] = rbar[w * 64 + tt * 16 + (lane & 15)];

  // ---- convert P f32->f16 EARLY, write Ph slab-wise (4 x ds_write_b64, 2-way-free) ----
  {
    uint2 w0, w1, w2, w3;
    w0.x = pk2(__uint_as_float(c0[0]), __uint_as_float(c0[1]));
    w0.y = pk2(__uint_as_float(c0[2]), __uint_as_float(c0[3]));
    w1.x = pk2(__uint_as_float(c1[0]), __uint_as_float(c1[1]));
    w1.y = pk2(__uint_as_float(c1[2]), __uint_as_float(c1[3]));
    w2.x = pk2(__uint_as_float(c2[0]), __uint_as_float(c2[1]));
    w2.y = pk2(__uint_as_float(c2[2]), __uint_as_float(c2[3]));
    w3.x = pk2(__uint_as_float(c3[0]), __uint_as_float(c3[1]));
    w3.y = pk2(__uint_as_float(c3[2]), __uint_as_float(c3[3]));
    *(uint2*)&UN[w][lane * 4]       = w0;   // f16 idx lane*4 .. +3
    *(uint2*)&UN[w][256 + lane * 4] = w1;
    *(uint2*)&UN[w][512 + lane * 4] = w2;
    *(uint2*)&UN[w][768 + lane * 4] = w3;
  }

  // ---- q~ via MFMA: C[vi][od] = sum_e x[v0+vi][e] A~[e][od] ----
  {
    const int od0 = w * 64;
    const uint4* xrow4 = (const uint4*)(xh + (size_t)(v0 + (lane & 3)) * 32);
    f16x8 afrag0 = u4h8(xrow4[(lane >> 4)]);       // K-step 0: e 0..31
    f16x8 afrag1 = u4h8(xrow4[4 + (lane >> 4)]);   // K-step 1: e 32..63

    f32x4 acc[4];
#pragma unroll
    for (int tt = 0; tt < 4; ++tt) acc[tt] = (f32x4){0.f, 0.f, 0.f, 0.f};

#pragma unroll
    for (int tt = 0; tt < 4; ++tt) {
      const int colbase = od0 + tt * 16 + (lane & 15);
#pragma unroll
      for (int s = 0; s < 2; ++s) {
        // B frag: one dwordx4 in quad-swizzled layout (eq = s*4 + (lane>>4))
        uint4 bu = *(const uint4*)&AhTs[((s * 4 + (lane >> 4)) * 256 + colbase) * 4];
        acc[tt] = __builtin_amdgcn_mfma_f32_16x16x32_f16(s ? afrag1 : afrag0, u4h8(bu),
                                                         acc[tt], 0, 0, 0);
      }
    }
    // C: col = lane&15, row = (lane>>4)*4 + reg ; rows 0..3 = vertices, lanes 0..15
    if (lane < 16) {
#pragma unroll
      for (int tt = 0; tt < 4; ++tt)
#pragma unroll
        for (int vi = 0; vi < 4; ++vi)
          q16[vi][od0 + tt * 16 + lane] = (_Float16)(acc[tt][vi] + rbq[tt]);
    }
  }
  __syncthreads();   // drains VMEM (X DMA) + LDS (Ph, q16); publishes q16 across waves

  // ---- hoisted scores B-frags (q16 stable from here) ----
  const int hb = (lane & 15) & 3;   // cols 4..15 duplicate h 0..3; outputs unused
  f16x8 bq0 = u4h8(*(const uint4*)&q16[w][hb * 64 + (lane >> 4) * 8]);
  f16x8 bq1 = u4h8(*(const uint4*)&q16[w][hb * 64 + 32 + (lane >> 4) * 8]);

  // ---- f' : lane = d = o*8+p ; P16 row (m*8+o), X16 row (m*8+p) ----
  const uint4* P16 = (const uint4*)&UN[w][0];
  const uint4* X16 = (const uint4*)&UN[w][1024];
  float freg[16];
#pragma unroll
  for (int m = 0; m < 16; ++m) {
    uint4 Pu = P16[m * 8 + o];
    uint4 Xu = X16[m * 8 + p];
    freg[m] = fdot2f(u2h(Pu.x), u2h(Xu.x),
              fdot2f(u2h(Pu.y), u2h(Xu.y),
              fdot2f(u2h(Pu.z), u2h(Xu.z),
              fdot2f(u2h(Pu.w), u2h(Xu.w), 0.f))));
  }
  lds_fence();   // REQUIRED: Ph/Xd reads must retire before Ftr overwrites the union

  // ---- transpose F to A-frag layout: Ftr[m][d] = UN[w][m*72+d] (aliases Ph/Xd) ----
#pragma unroll
  for (int m = 0; m < 16; ++m) UN[w][m * 72 + lane] = (_Float16)freg[m];
  lds_fence();   // Ftr writes visible before reads

  // ---- scores via MFMA: S[m][h] = sum_d F[m][d] q16[h][d] ----
  f32x4 sac = (f32x4){0.f, 0.f, 0.f, 0.f};
  {
    f16x8 af0 = u4h8(*(const uint4*)&UN[w][(lane & 15) * 72 + (lane >> 4) * 8]);
    f16x8 af1 = u4h8(*(const uint4*)&UN[w][(lane & 15) * 72 + 32 + (lane >> 4) * 8]);
    sac = __builtin_amdgcn_mfma_f32_16x16x32_f16(af0, bq0, sac, 0, 0, 0);
    sac = __builtin_amdgcn_mfma_f32_16x16x32_f16(af1, bq1, sac, 0, 0, 0);
    // lane holds S[m=(lane>>4)*4+r][h=lane&15], r=0..3 (h<4 meaningful)
  }

  // ---- no-max softmax: raw exp, normalization deferred to g (|s| << 88) ----
  {
    float e0 = __expf(sac[0]), e1 = __expf(sac[1]);
    float e2 = __expf(sac[2]), e3 = __expf(sac[3]);
    if ((lane & 15) < 4) {
      const int h = lane & 15, mb = (lane >> 4) * 4;
      attn_lds[w][(mb + 0) * 4 + h] = e0;
      attn_lds[w][(mb + 1) * 4 + h] = e1;
      attn_lds[w][(mb + 2) * 4 + h] = e2;
      attn_lds[w][(mb + 3) * 4 + h] = e3;
    }
  }
  lds_fence();

  // ---- epilogue weights (late load, overlaps g compute) ----
  uint4 wq[4];
#pragma unroll
  for (int h = 0; h < 4; ++h) wq[h] = *(const uint4*)&wvh[i_ep * 16 + h * 4];

  // ---- g[h][d] = (sum_m e[m][h] f'[m][d]) / (sum_m e[m][h]) ; lane = d ----
  float g[4] = {0.f, 0.f, 0.f, 0.f};
  float s4[4] = {0.f, 0.f, 0.f, 0.f};
#pragma unroll
  for (int m = 0; m < 16; ++m) {
    float4 a4 = *(const float4*)&attn_lds[w][m * 4];   // broadcast read
    g[0] = fmaf(a4.x, freg[m], g[0]);
    g[1] = fmaf(a4.y, freg[m], g[1]);
    g[2] = fmaf(a4.z, freg[m], g[2]);
    g[3] = fmaf(a4.w, freg[m], g[3]);
    s4[0] += a4.x; s4[1] += a4.y; s4[2] += a4.z; s4[3] += a4.w;
  }

  // ---- W_V epilogue via f16 tile + dot2 (normalize folded into the f16 cast) ----
#pragma unroll
  for (int h = 0; h < 4; ++h) g16[w][h][lane] = (_Float16)(g[h] / s4[h]);
  lds_fence();
#pragma unroll
  for (int h = 0; h < 4; ++h) {
    uint4 gq = *(const uint4*)&g16[w][h][c_ep * 8];
    float oacc = fdot2f(u2h(wq[h].x), u2h(gq.x),
                 fdot2f(u2h(wq[h].y), u2h(gq.y),
                 fdot2f(u2h(wq[h].z), u2h(gq.z),
                 fdot2f(u2h(wq[h].w), u2h(gq.w), 0.f))));
    __builtin_nontemporal_store(oacc, &out[(size_t)v * 256 + h * 64 + lane]);
  }
}

extern "C" void kernel_launch(void* const* d_in, const int* in_sizes, int n_in,
                              void* d_out, int out_size, void* d_ws, size_t ws_size,
                              hipStream_t stream) {
  const float* x      = (const float*)d_in[0];
  const int*   nbr    = (const int*)d_in[1];
  const float* P      = (const float*)d_in[2];
  // d_in[3] = rel_pos_u : unused by the reference
  const float* WQ     = (const float*)d_in[4];
  const float* WQb    = (const float*)d_in[5];
  const float* WK     = (const float*)d_in[6];
  // d_in[7] = W_K_b : softmax-invariant -> dropped
  const float* bases  = (const float*)d_in[8];
  const float* coeffs = (const float*)d_in[9];

  unsigned* AhTs = (unsigned*)d_ws;
  float* rbar   = (float*)((char*)d_ws + 32768);
  unsigned* wvh = (unsigned*)((char*)d_ws + 33792);
  unsigned* xh  = (unsigned*)((char*)d_ws + 34816);
  float* out    = (float*)d_out;

  hipLaunchKernelGGL(prep_kernel, dim3(32 + (NV * 8 + 255) / 256), dim3(256), 0, stream,
                     WQ, WQb, WK, bases, coeffs, x, AhTs, rbar, wvh, xh);
  hipLaunchKernelGGL(attn_kernel, dim3(NV / 4), dim3(256), 0, stream,
                     xh, nbr, P, AhTs, rbar, wvh, out);
}

// Round 6
// 78.150 us; speedup vs baseline: 1.1524x; 1.0442x over previous
//
#include <hip/hip_runtime.h>
#include <hip/hip_bf16.h>

#define NV 50000

// ws layout:
//   [0, 32768)        AhTs packed f16x2, B-frag quad order: [eq=ep>>2][od][r=ep&3]
//   [32768, 33792)    rbar f32 [256]
//   [33792, 34304)    wvh  packed f16x2 [8 i][4 h][4 jp] (W_V)
//   [34816, +6.4MB)   xh   packed f16x2 [NV][32]         (x converted)

typedef _Float16 h2_t __attribute__((ext_vector_type(2)));
typedef _Float16 f16x8 __attribute__((ext_vector_type(8)));
typedef float f32x4 __attribute__((ext_vector_type(4)));
typedef unsigned u32x4 __attribute__((ext_vector_type(4)));

#if defined(__has_builtin)
#if __has_builtin(__builtin_amdgcn_fdot2)
#define HAVE_FDOT2 1
#endif
#endif

__device__ __forceinline__ float fdot2f(h2_t a, h2_t b, float c) {
#ifdef HAVE_FDOT2
  return __builtin_amdgcn_fdot2(a, b, c, false);
#else
  return fmaf((float)a.x, (float)b.x, fmaf((float)a.y, (float)b.y, c));
#endif
}
__device__ __forceinline__ h2_t u2h(unsigned u) {
  union { unsigned u; h2_t h; } c; c.u = u; return c.h;
}
__device__ __forceinline__ unsigned pk2(float a, float b) {
  auto v = __builtin_amdgcn_cvt_pkrtz(a, b);   // __fp16 ext_vector(2)
  union { decltype(v) h; unsigned u; } c; c.h = v; return c.u;
}
__device__ __forceinline__ f16x8 u4h8(uint4 u) {
  union { uint4 u; f16x8 h; } c; c.u = u; return c.h;
}
// IR-level memory clobber + HW LDS drain + scheduler pin (rule #18)
__device__ __forceinline__ void lds_fence() {
  asm volatile("s_waitcnt lgkmcnt(0)" ::: "memory");
  __builtin_amdgcn_sched_barrier(0);
}

// setup (blocks 0..31) + xconv (blocks 32..) fused: one launch
__global__ void prep_kernel(const float* __restrict__ WQ, const float* __restrict__ WQb,
                            const float* __restrict__ WK,
                            const float* __restrict__ bases, const float* __restrict__ coeffs,
                            const float* __restrict__ x,
                            unsigned* __restrict__ AhTs, float* __restrict__ rbar,
                            unsigned* __restrict__ wvh, unsigned* __restrict__ xh) {
  if (blockIdx.x < 32) {
    int ep = blockIdx.x;      // 0..31 (e-pair)
    int od = threadIdx.x;     // 0..255 : h*64+d
    int h = od >> 6, d = od & 63;
    int e0 = ep * 2;
    float s0 = 0.f, s1 = 0.f;
#pragma unroll 4
    for (int k = 0; k < 64; ++k) {
      float wk = WK[(h * 64 + k) * 64 + d];
      s0 += WQ[(h * 64 + k) * 64 + e0] * wk;
      s1 += WQ[(h * 64 + k) * 64 + e0 + 1] * wk;
    }
    // B-frag quad order: one uint4 = eps {eq*4+0..3} for a fixed od
    AhTs[((ep >> 2) * 256 + od) * 4 + (ep & 3)] = pk2(s0 * 0.125f, s1 * 0.125f);
    if (ep == 0) {
      float r = 0.f;
      for (int k = 0; k < 64; ++k) r += WQb[h * 64 + k] * WK[(h * 64 + k) * 64 + d];
      rbar[od] = r * 0.125f;
      if (od < 128) {   // wvh[i][h][jp]
        int i = od >> 4, hh = (od >> 2) & 3, jp = od & 3;
        float w0 = 0.f, w1 = 0.f;
        for (int b = 0; b < 6; ++b) {
          w0 += coeffs[hh * 6 + b] * bases[b * 64 + i * 8 + 2 * jp];
          w1 += coeffs[hh * 6 + b] * bases[b * 64 + i * 8 + 2 * jp + 1];
        }
        wvh[od] = pk2(w0, w1);
      }
    }
  } else {
    int idx = (blockIdx.x - 32) * 256 + threadIdx.x;   // uint4 index, 0 .. NV*8-1
    if (idx < NV * 8) {
      float4 a = ((const float4*)x)[idx * 2];
      float4 b = ((const float4*)x)[idx * 2 + 1];
      uint4 o;
      o.x = pk2(a.x, a.y);
      o.y = pk2(a.z, a.w);
      o.z = pk2(b.x, b.y);
      o.w = pk2(b.z, b.w);
      ((uint4*)xh)[idx] = o;
    }
  }
}

__device__ __forceinline__ void gload_lds16(const void* g, void* l) {
  __builtin_amdgcn_global_load_lds((const __attribute__((address_space(1))) void*)g,
                                   (__attribute__((address_space(3))) void*)l, 16, 0, 0);
}

// ---------------- attention: 1 wave = 2 vertices (va = v0+w, vb = v0+4+w), software-pipelined:
//  ALL of vb's memory (P nt-loads, X DMA) issued at wave start -> in flight under va's compute.
//  One barrier + one AhTs B-frag load set serves both vertices.
//  LDS/wave: UN 3KB {A=Ph, B=Xd(va), C=Xd(vb)}; Ftr/attn/g16 reused va->vb with fences. ----------------
__global__ __launch_bounds__(256, 4) void attn_kernel(
    const unsigned* __restrict__ xh, const int* __restrict__ nbr,
    const float* __restrict__ P, const unsigned* __restrict__ AhTs,
    const float* __restrict__ rbar, const unsigned* __restrict__ wvh,
    float* __restrict__ out) {
  __shared__ __align__(16) _Float16 UN[4][3072];     // 24 KB: A=[0,1024) Ph, B=[1024,2048) Xd(va), C=[2048,3072) Xd(vb)
  __shared__ __align__(16) _Float16 Ftr[4][1152];    // 9 KB   [m][72-stride] f16
  __shared__ __align__(16) _Float16 q16[8][256];     // 4 KB   [vi 0..7][h*64+d]
  __shared__ __align__(16) float    attn_lds[4][64]; // 1 KB
  __shared__ __align__(16) _Float16 g16[4][4][64];   // 2 KB   -> 40 KB total

  const int t = threadIdx.x;
  const int w = t >> 6, lane = t & 63;
  const int v0 = blockIdx.x * 8;
  const int va = v0 + w, vb = v0 + 4 + w;
  const int o = lane >> 3, p = lane & 7;
  const int c_ep = lane >> 3, i_ep = lane & 7;
  const char* xhb = (const char*)xh;

  // ---- neighbor indices (both vertices) ----
  int nbA0 = nbr[(size_t)va * 16 + (lane >> 3)];
  int nbA1 = nbr[(size_t)va * 16 + 8 + (lane >> 3)];
  int nbB0 = nbr[(size_t)vb * 16 + (lane >> 3)];
  int nbB1 = nbr[(size_t)vb * 16 + 8 + (lane >> 3)];

  // ---- P loads for BOTH vertices, coalesced + non-temporal (8 x b128 in flight) ----
  u32x4 a0, a1, a2, a3, b0, b1, b2, b3;
  {
    const u32x4* PgA = (const u32x4*)(P + (size_t)va * 1024);
    const u32x4* PgB = (const u32x4*)(P + (size_t)vb * 1024);
    a0 = __builtin_nontemporal_load(PgA + lane);
    a1 = __builtin_nontemporal_load(PgA + 64 + lane);
    a2 = __builtin_nontemporal_load(PgA + 128 + lane);
    a3 = __builtin_nontemporal_load(PgA + 192 + lane);
    b0 = __builtin_nontemporal_load(PgB + lane);
    b1 = __builtin_nontemporal_load(PgB + 64 + lane);
    b2 = __builtin_nontemporal_load(PgB + 128 + lane);
    b3 = __builtin_nontemporal_load(PgB + 192 + lane);
  }

  // ---- X DMA for BOTH vertices (4 x 1KB) ----
  gload_lds16(xhb + (size_t)nbA0 * 128 + (lane & 7) * 16, &UN[w][1024]);
  gload_lds16(xhb + (size_t)nbA1 * 128 + (lane & 7) * 16, &UN[w][1536]);
  gload_lds16(xhb + (size_t)nbB0 * 128 + (lane & 7) * 16, &UN[w][2048]);
  gload_lds16(xhb + (size_t)nbB1 * 128 + (lane & 7) * 16, &UN[w][2560]);

  // ---- rbar (od = w*64 + tt*16 + lane&15) ----
  float rbq[4];
#pragma unroll
  for (int tt = 0; tt < 4; ++tt) rbq[tt] = rbar[w * 64 + tt * 16 + (lane & 15)];

  // ---- convert P(va) f32->f16, write Ph = UN[w][0..1024) slab-wise ----
  {
    uint2 w0, w1, w2, w3;
    w0.x = pk2(__uint_as_float(a0[0]), __uint_as_float(a0[1]));
    w0.y = pk2(__uint_as_float(a0[2]), __uint_as_float(a0[3]));
    w1.x = pk2(__uint_as_float(a1[0]), __uint_as_float(a1[1]));
    w1.y = pk2(__uint_as_float(a1[2]), __uint_as_float(a1[3]));
    w2.x = pk2(__uint_as_float(a2[0]), __uint_as_float(a2[1]));
    w2.y = pk2(__uint_as_float(a2[2]), __uint_as_float(a2[3]));
    w3.x = pk2(__uint_as_float(a3[0]), __uint_as_float(a3[1]));
    w3.y = pk2(__uint_as_float(a3[2]), __uint_as_float(a3[3]));
    *(uint2*)&UN[w][lane * 4]       = w0;
    *(uint2*)&UN[w][256 + lane * 4] = w1;
    *(uint2*)&UN[w][512 + lane * 4] = w2;
    *(uint2*)&UN[w][768 + lane * 4] = w3;
  }

  // ---- q~ via MFMA for all 8 block vertices; one AhTs B-frag load set ----
  {
    const int od0 = w * 64;
    uint4 bu[2][4];
#pragma unroll
    for (int s = 0; s < 2; ++s)
#pragma unroll
      for (int tt = 0; tt < 4; ++tt)
        bu[s][tt] = *(const uint4*)&AhTs[((s * 4 + (lane >> 4)) * 256 + od0 + tt * 16 + (lane & 15)) * 4];

    // pass a: vertices v0+0..3
    {
      const uint4* xr = (const uint4*)(xh + (size_t)(v0 + (lane & 3)) * 32);
      f16x8 af0 = u4h8(xr[(lane >> 4)]);
      f16x8 af1 = u4h8(xr[4 + (lane >> 4)]);
      f32x4 acc[4];
#pragma unroll
      for (int tt = 0; tt < 4; ++tt) acc[tt] = (f32x4){0.f, 0.f, 0.f, 0.f};
#pragma unroll
      for (int tt = 0; tt < 4; ++tt)
#pragma unroll
        for (int s = 0; s < 2; ++s)
          acc[tt] = __builtin_amdgcn_mfma_f32_16x16x32_f16(s ? af1 : af0, u4h8(bu[s][tt]),
                                                           acc[tt], 0, 0, 0);
      if (lane < 16) {
#pragma unroll
        for (int tt = 0; tt < 4; ++tt)
#pragma unroll
          for (int vi = 0; vi < 4; ++vi)
            q16[vi][od0 + tt * 16 + lane] = (_Float16)(acc[tt][vi] + rbq[tt]);
      }
    }
    // pass b: vertices v0+4..7
    {
      const uint4* xr = (const uint4*)(xh + (size_t)(v0 + 4 + (lane & 3)) * 32);
      f16x8 af0 = u4h8(xr[(lane >> 4)]);
      f16x8 af1 = u4h8(xr[4 + (lane >> 4)]);
      f32x4 acc[4];
#pragma unroll
      for (int tt = 0; tt < 4; ++tt) acc[tt] = (f32x4){0.f, 0.f, 0.f, 0.f};
#pragma unroll
      for (int tt = 0; tt < 4; ++tt)
#pragma unroll
        for (int s = 0; s < 2; ++s)
          acc[tt] = __builtin_amdgcn_mfma_f32_16x16x32_f16(s ? af1 : af0, u4h8(bu[s][tt]),
                                                           acc[tt], 0, 0, 0);
      if (lane < 16) {
#pragma unroll
        for (int tt = 0; tt < 4; ++tt)
#pragma unroll
          for (int vi = 0; vi < 4; ++vi)
            q16[4 + vi][od0 + tt * 16 + lane] = (_Float16)(acc[tt][vi] + rbq[tt]);
      }
    }
  }
  __syncthreads();   // drains VMEM (X DMAs, P(vb) already arrived) + LDS; publishes q16

  // ---- epilogue weights (shared by both vertices) ----
  uint4 wq[4];
#pragma unroll
  for (int h = 0; h < 4; ++h) wq[h] = *(const uint4*)&wvh[i_ep * 16 + h * 4];

  const int hb = (lane & 15) & 3;
  const int rowA = (lane & 15) * 72 + (lane >> 4) * 8;

  // ================= vertex va =================
  f16x8 bq0 = u4h8(*(const uint4*)&q16[w][hb * 64 + (lane >> 4) * 8]);
  f16x8 bq1 = u4h8(*(const uint4*)&q16[w][hb * 64 + 32 + (lane >> 4) * 8]);

  // ---- f'(va): Ph=UN[w][0..), Xd=UN[w][1024..) ----
  float freg[16];
  {
    const uint4* P16 = (const uint4*)&UN[w][0];
    const uint4* X16 = (const uint4*)&UN[w][1024];
#pragma unroll
    for (int m = 0; m < 16; ++m) {
      uint4 Pu = P16[m * 8 + o];
      uint4 Xu = X16[m * 8 + p];
      freg[m] = fdot2f(u2h(Pu.x), u2h(Xu.x),
                fdot2f(u2h(Pu.y), u2h(Xu.y),
                fdot2f(u2h(Pu.z), u2h(Xu.z),
                fdot2f(u2h(Pu.w), u2h(Xu.w), 0.f))));
    }
  }
  lds_fence();   // Ph/Xd(va) reads retire before Ftr + Ph(vb) writes

  // ---- Ftr(va) + convert P(vb) -> Ph (same epoch; both fenced before reads) ----
#pragma unroll
  for (int m = 0; m < 16; ++m) Ftr[w][m * 72 + lane] = (_Float16)freg[m];
  {
    uint2 w0, w1, w2, w3;
    w0.x = pk2(__uint_as_float(b0[0]), __uint_as_float(b0[1]));
    w0.y = pk2(__uint_as_float(b0[2]), __uint_as_float(b0[3]));
    w1.x = pk2(__uint_as_float(b1[0]), __uint_as_float(b1[1]));
    w1.y = pk2(__uint_as_float(b1[2]), __uint_as_float(b1[3]));
    w2.x = pk2(__uint_as_float(b2[0]), __uint_as_float(b2[1]));
    w2.y = pk2(__uint_as_float(b2[2]), __uint_as_float(b2[3]));
    w3.x = pk2(__uint_as_float(b3[0]), __uint_as_float(b3[1]));
    w3.y = pk2(__uint_as_float(b3[2]), __uint_as_float(b3[3]));
    *(uint2*)&UN[w][lane * 4]       = w0;
    *(uint2*)&UN[w][256 + lane * 4] = w1;
    *(uint2*)&UN[w][512 + lane * 4] = w2;
    *(uint2*)&UN[w][768 + lane * 4] = w3;
  }
  lds_fence();

  // ---- scores(va) ----
  f32x4 sac = (f32x4){0.f, 0.f, 0.f, 0.f};
  {
    f16x8 af0 = u4h8(*(const uint4*)&Ftr[w][rowA]);
    f16x8 af1 = u4h8(*(const uint4*)&Ftr[w][rowA + 32]);
    sac = __builtin_amdgcn_mfma_f32_16x16x32_f16(af0, bq0, sac, 0, 0, 0);
    sac = __builtin_amdgcn_mfma_f32_16x16x32_f16(af1, bq1, sac, 0, 0, 0);
  }
  // ---- no-max softmax(va) ----
  {
    float e0 = __expf(sac[0]), e1 = __expf(sac[1]);
    float e2 = __expf(sac[2]), e3 = __expf(sac[3]);
    if ((lane & 15) < 4) {
      const int h = lane & 15, mb = (lane >> 4) * 4;
      attn_lds[w][(mb + 0) * 4 + h] = e0;
      attn_lds[w][(mb + 1) * 4 + h] = e1;
      attn_lds[w][(mb + 2) * 4 + h] = e2;
      attn_lds[w][(mb + 3) * 4 + h] = e3;
    }
  }
  lds_fence();

  // ---- g(va) ----
  {
    float g[4] = {0.f, 0.f, 0.f, 0.f};
    float s4[4] = {0.f, 0.f, 0.f, 0.f};
#pragma unroll
    for (int m = 0; m < 16; ++m) {
      float4 a4 = *(const float4*)&attn_lds[w][m * 4];
      g[0] = fmaf(a4.x, freg[m], g[0]);
      g[1] = fmaf(a4.y, freg[m], g[1]);
      g[2] = fmaf(a4.z, freg[m], g[2]);
      g[3] = fmaf(a4.w, freg[m], g[3]);
      s4[0] += a4.x; s4[1] += a4.y; s4[2] += a4.z; s4[3] += a4.w;
    }
#pragma unroll
    for (int h = 0; h < 4; ++h) g16[w][h][lane] = (_Float16)(g[h] / s4[h]);
  }
  lds_fence();
#pragma unroll
  for (int h = 0; h < 4; ++h) {
    uint4 gq = *(const uint4*)&g16[w][h][c_ep * 8];
    float oacc = fdot2f(u2h(wq[h].x), u2h(gq.x),
                 fdot2f(u2h(wq[h].y), u2h(gq.y),
                 fdot2f(u2h(wq[h].z), u2h(gq.z),
                 fdot2f(u2h(wq[h].w), u2h(gq.w), 0.f))));
    __builtin_nontemporal_store(oacc, &out[(size_t)va * 256 + h * 64 + lane]);
  }

  // ================= vertex vb =================
  bq0 = u4h8(*(const uint4*)&q16[4 + w][hb * 64 + (lane >> 4) * 8]);
  bq1 = u4h8(*(const uint4*)&q16[4 + w][hb * 64 + 32 + (lane >> 4) * 8]);

  // ---- f'(vb): Ph=UN[w][0..) (P(vb), fenced), Xd=UN[w][2048..) ----
  {
    const uint4* P16 = (const uint4*)&UN[w][0];
    const uint4* X16 = (const uint4*)&UN[w][2048];
#pragma unroll
    for (int m = 0; m < 16; ++m) {
      uint4 Pu = P16[m * 8 + o];
      uint4 Xu = X16[m * 8 + p];
      freg[m] = fdot2f(u2h(Pu.x), u2h(Xu.x),
                fdot2f(u2h(Pu.y), u2h(Xu.y),
                fdot2f(u2h(Pu.z), u2h(Xu.z),
                fdot2f(u2h(Pu.w), u2h(Xu.w), 0.f))));
    }
  }
  // Ftr region last read at scores(va) (fenced since); no hazard with f'(vb) reads
#pragma unroll
  for (int m = 0; m < 16; ++m) Ftr[w][m * 72 + lane] = (_Float16)freg[m];
  lds_fence();

  // ---- scores(vb) ----
  sac = (f32x4){0.f, 0.f, 0.f, 0.f};
  {
    f16x8 af0 = u4h8(*(const uint4*)&Ftr[w][rowA]);
    f16x8 af1 = u4h8(*(const uint4*)&Ftr[w][rowA + 32]);
    sac = __builtin_amdgcn_mfma_f32_16x16x32_f16(af0, bq0, sac, 0, 0, 0);
    sac = __builtin_amdgcn_mfma_f32_16x16x32_f16(af1, bq1, sac, 0, 0, 0);
  }
  // ---- no-max softmax(vb) ----
  {
    float e0 = __expf(sac[0]), e1 = __expf(sac[1]);
    float e2 = __expf(sac[2]), e3 = __expf(sac[3]);
    if ((lane & 15) < 4) {
      const int h = lane & 15, mb = (lane >> 4) * 4;
      attn_lds[w][(mb + 0) * 4 + h] = e0;
      attn_lds[w][(mb + 1) * 4 + h] = e1;
      attn_lds[w][(mb + 2) * 4 + h] = e2;
      attn_lds[w][(mb + 3) * 4 + h] = e3;
    }
  }
  lds_fence();

  // ---- g(vb) ----
  {
    float g[4] = {0.f, 0.f, 0.f, 0.f};
    float s4[4] = {0.f, 0.f, 0.f, 0.f};
#pragma unroll
    for (int m = 0; m < 16; ++m) {
      float4 a4 = *(const float4*)&attn_lds[w][m * 4];
      g[0] = fmaf(a4.x, freg[m], g[0]);
      g[1] = fmaf(a4.y, freg[m], g[1]);
      g[2] = fmaf(a4.z, freg[m], g[2]);
      g[3] = fmaf(a4.w, freg[m], g[3]);
      s4[0] += a4.x; s4[1] += a4.y; s4[2] += a4.z; s4[3] += a4.w;
    }
#pragma unroll
    for (int h = 0; h < 4; ++h) g16[w][h][lane] = (_Float16)(g[h] / s4[h]);
  }
  lds_fence();
#pragma unroll
  for (int h = 0; h < 4; ++h) {
    uint4 gq = *(const uint4*)&g16[w][h][c_ep * 8];
    float oacc = fdot2f(u2h(wq[h].x), u2h(gq.x),
                 fdot2f(u2h(wq[h].y), u2h(gq.y),
                 fdot2f(u2h(wq[h].z), u2h(gq.z),
                 fdot2f(u2h(wq[h].w), u2h(gq.w), 0.f))));
    __builtin_nontemporal_store(oacc, &out[(size_t)vb * 256 + h * 64 + lane]);
  }
}

extern "C" void kernel_launch(void* const* d_in, const int* in_sizes, int n_in,
                              void* d_out, int out_size, void* d_ws, size_t ws_size,
                              hipStream_t stream) {
  const float* x      = (const float*)d_in[0];
  const int*   nbr    = (const int*)d_in[1];
  const float* P      = (const float*)d_in[2];
  // d_in[3] = rel_pos_u : unused by the reference
  const float* WQ     = (const float*)d_in[4];
  const float* WQb    = (const float*)d_in[5];
  const float* WK     = (const float*)d_in[6];
  // d_in[7] = W_K_b : softmax-invariant -> dropped
  const float* bases  = (const float*)d_in[8];
  const float* coeffs = (const float*)d_in[9];

  unsigned* AhTs = (unsigned*)d_ws;
  float* rbar   = (float*)((char*)d_ws + 32768);
  unsigned* wvh = (unsigned*)((char*)d_ws + 33792);
  unsigned* xh  = (unsigned*)((char*)d_ws + 34816);
  float* out    = (float*)d_out;

  hipLaunchKernelGGL(prep_kernel, dim3(32 + (NV * 8 + 255) / 256), dim3(256), 0, stream,
                     WQ, WQb, WK, bases, coeffs, x, AhTs, rbar, wvh, xh);
  hipLaunchKernelGGL(attn_kernel, dim3(NV / 8), dim3(256), 0, stream,
                     xh, nbr, P, AhTs, rbar, wvh, out);
}